// Round 7
// baseline (397.857 us; speedup 1.0000x reference)
//
#include <hip/hip_runtime.h>
#include <hip/hip_bf16.h>
#include <math.h>

constexpr int DM = 1024;    // d_model
constexpr int NH = 16;      // heads
constexpr int DK = 64;      // head dim
constexpr int SQ = 2048;    // seq len
constexpr int BB = 2;       // batch
constexpr int MR = BB * SQ; // 4096 rows

typedef short bf16x8 __attribute__((ext_vector_type(8)));
typedef float f32x4 __attribute__((ext_vector_type(4)));

__device__ inline unsigned short f2bf(float f) {
  unsigned u = __float_as_uint(f);
  unsigned r = (u + 0x7fffu + ((u >> 16) & 1u)) >> 16;  // RNE
  return (unsigned short)r;
}

// XOR-swizzled element index for a [R][64] bf16 LDS tile.
__device__ inline int swz(int r, int c) {
  int f = (r & 7) ^ ((r >> 3) & 7);
  return r * 64 + ((((c >> 3) ^ f) & 7) << 3) + (c & 7);
}

// -------- cast f32 -> bf16, 8 elems/thread --------
__global__ __launch_bounds__(256)
void cast_kernel(const float* __restrict__ in, unsigned short* __restrict__ out, int n8) {
  int i = blockIdx.x * 256 + threadIdx.x;
  if (i >= n8) return;
  float4 a = *(const float4*)&in[(size_t)i * 8];
  float4 b = *(const float4*)&in[(size_t)i * 8 + 4];
  ushort4 lo = {f2bf(a.x), f2bf(a.y), f2bf(a.z), f2bf(a.w)};
  ushort4 hi = {f2bf(b.x), f2bf(b.y), f2bf(b.z), f2bf(b.w)};
  *(ushort4*)&out[(size_t)i * 8] = lo;
  *(ushort4*)&out[(size_t)i * 8 + 4] = hi;
}

// -------- cast+transpose: W[K][N] f32 -> Wt[N][K] bf16 (32x32 tiles) --------
__global__ __launch_bounds__(256)
void transpose_cast_kernel(const float* __restrict__ W, unsigned short* __restrict__ Wt) {
  __shared__ float tl[32][33];
  const int tx = threadIdx.x & 31, ty = threadIdx.x >> 5;  // 32 x 8
  const int x0 = blockIdx.x * 32, y0 = blockIdx.y * 32;    // x0: n, y0: k
  #pragma unroll
  for (int i = 0; i < 4; ++i)
    tl[ty + i * 8][tx] = W[(size_t)(y0 + ty + i * 8) * DM + x0 + tx];
  __syncthreads();
  #pragma unroll
  for (int i = 0; i < 4; ++i)
    Wt[(size_t)(x0 + ty + i * 8) * DM + y0 + tx] = f2bf(tl[tx][ty + i * 8]);
}

// -------- bf16 MFMA GEMM: out = A[M,1024] * Wt[N,1024]^T + bias --------
// Tile 128x64 (grid 16x32 = 512 blocks = 2/CU).
// MODE 0: out f32 row-major [M,N].
// MODE 1: out bf16 remapped [B,H,S,DK]   (Q, K)
// MODE 2: out bf16 remapped [B,H,DK,S]   (V transposed for attention)
template<int MODE>
__global__ __launch_bounds__(256)
void mfma_gemm(const unsigned short* __restrict__ A, const unsigned short* __restrict__ Bt,
               const float* __restrict__ bias, void* __restrict__ outp)
{
  constexpr int K = DM, N = DM;
  constexpr int LDT = 72;                   // padded LDS row (144B): <=2-way banks
  __shared__ unsigned short As[128 * LDT];
  __shared__ unsigned short Bs[64 * LDT];
  const int t = threadIdx.x;
  const int w = t >> 6, ln = t & 63;
  const int wr = w >> 1, wc = w & 1;        // 2x2 wave grid: 64 rows x 32 cols each
  const int rb = blockIdx.y * 128, cb = blockIdx.x * 64;

  f32x4 acc[4][2] = {};

  for (int k0 = 0; k0 < K; k0 += 64) {
    // A tile 128x64 = 1024 granules (4/thread); B tile 64x64 = 512 (2/thread)
    uint4 ag[4], bg[2];
    #pragma unroll
    for (int i = 0; i < 4; ++i) {
      const int g = t + i * 256;
      const int r = g >> 3, c = (g & 7) * 8;
      ag[i] = *(const uint4*)&A[(size_t)(rb + r) * K + k0 + c];
    }
    #pragma unroll
    for (int i = 0; i < 2; ++i) {
      const int g = t + i * 256;
      const int r = g >> 3, c = (g & 7) * 8;
      bg[i] = *(const uint4*)&Bt[(size_t)(cb + r) * K + k0 + c];
    }
    __syncthreads();  // protect previous iteration's LDS reads
    #pragma unroll
    for (int i = 0; i < 4; ++i) {
      const int g = t + i * 256;
      const int r = g >> 3, c = (g & 7) * 8;
      *(uint4*)&As[r * LDT + c] = ag[i];
    }
    #pragma unroll
    for (int i = 0; i < 2; ++i) {
      const int g = t + i * 256;
      const int r = g >> 3, c = (g & 7) * 8;
      *(uint4*)&Bs[r * LDT + c] = bg[i];
    }
    __syncthreads();

    #pragma unroll
    for (int kk = 0; kk < 2; ++kk) {
      const int ko = kk * 32 + (ln >> 4) * 8;   // lane-group k offset
      const int rsel = ln & 15;
      bf16x8 af[4], bf[2];
      #pragma unroll
      for (int m = 0; m < 4; ++m)
        af[m] = *(const bf16x8*)&As[(wr * 64 + m * 16 + rsel) * LDT + ko];
      #pragma unroll
      for (int n = 0; n < 2; ++n)
        bf[n] = *(const bf16x8*)&Bs[(wc * 32 + n * 16 + rsel) * LDT + ko];
      #pragma unroll
      for (int m = 0; m < 4; ++m)
        #pragma unroll
        for (int n = 0; n < 2; ++n)
          acc[m][n] = __builtin_amdgcn_mfma_f32_16x16x32_bf16(af[m], bf[n], acc[m][n], 0, 0, 0);
    }
  }

  // epilogue: C/D layout col = ln&15, row = (ln>>4)*4 + i
  const int cl = ln & 15, rg = (ln >> 4) * 4;
  #pragma unroll
  for (int m = 0; m < 4; ++m) {
    #pragma unroll
    for (int i = 0; i < 4; ++i) {
      const int r = rb + wr * 64 + m * 16 + rg + i;
      #pragma unroll
      for (int n = 0; n < 2; ++n) {
        const int c = cb + wc * 32 + n * 16 + cl;
        const float v = acc[m][n][i] + bias[c];
        if (MODE == 0) {
          ((float*)outp)[(size_t)r * N + c] = v;
        } else {
          const int b = r >> 11, s = r & 2047;  // r = b*2048 + s
          const int h = c >> 6, d = c & 63;     // c = h*64 + d
          if (MODE == 1)
            ((unsigned short*)outp)[(((size_t)(b * NH + h)) * SQ + s) * DK + d] = f2bf(v);
          else  // MODE 2: V^T  [B,H,DK,S]
            ((unsigned short*)outp)[(((size_t)(b * NH + h)) * DK + d) * SQ + s] = f2bf(v);
        }
      }
    }
  }
}

// -------- MFMA flash attention --------
// Block = 4 waves, Q-tile 64 (16 rows/wave), KV-tile 64.
// Swapped QK^T (mfma(K,Q) -> S^T). V arrives pre-transposed [B,H,DK,S]:
// V^T tile staged with the same vectorized swizzled b128 path as K.
__global__ __launch_bounds__(256)
void attn_mfma(const unsigned short* __restrict__ Qp, const unsigned short* __restrict__ Kp,
               const unsigned short* __restrict__ Vp, unsigned short* __restrict__ ctx)
{
  __shared__ unsigned short Qs[64 * 64];
  __shared__ unsigned short Ks[64 * 64];
  __shared__ unsigned short Vt[64 * 64];      // V^T: [d][kv]
  __shared__ unsigned short Pl[4 * 16 * 64];  // per-wave P: [q][kk]
  const int t = threadIdx.x, w = t >> 6, ln = t & 63;
  const int bh = blockIdx.y, q0 = blockIdx.x * 64;
  const float scale = 0.125f;  // 1/sqrt(64), folded into exp args
  const unsigned short* Qb = Qp + (size_t)bh * SQ * DK;
  const unsigned short* Kb = Kp + (size_t)bh * SQ * DK;
  const unsigned short* Vb = Vp + (size_t)bh * DK * SQ;  // [DK][SQ]

  // stage Q tile (swizzled), then hoist this wave's B-fragments into regs
  #pragma unroll
  for (int i = 0; i < 2; ++i) {
    int g = t + i * 256, r = g >> 3, cg = g & 7;
    uint4 qv = *(const uint4*)&Qb[(size_t)(q0 + r) * DK + cg * 8];
    int f = (r & 7) ^ ((r >> 3) & 7);
    *(uint4*)&Qs[r * 64 + (((cg ^ f) & 7) << 3)] = qv;
  }
  __syncthreads();
  const int rsel = ln & 15, ko = (ln >> 4) * 8;
  bf16x8 qf[2];
  qf[0] = *(const bf16x8*)&Qs[swz(w * 16 + rsel, ko)];
  qf[1] = *(const bf16x8*)&Qs[swz(w * 16 + rsel, ko + 32)];

  f32x4 acc2[4] = {};          // O accum: O[q=(ln>>4)*4+i][d=16n+rsel]
  float m = -1e30f, l = 0.f;   // per-lane state for q-row = rsel

  // preload KV tile 0 into regs (K rows: kv; V^T rows: d)
  uint4 kg[2], vg[2];
  #pragma unroll
  for (int i = 0; i < 2; ++i) {
    int g = t + i * 256, r = g >> 3, cg = g & 7;
    kg[i] = *(const uint4*)&Kb[(size_t)r * DK + cg * 8];
    vg[i] = *(const uint4*)&Vb[(size_t)r * SQ + cg * 8];
  }

  for (int c0 = 0; c0 < SQ; c0 += 64) {
    __syncthreads();  // previous tile's Ks/Vt reads done
    #pragma unroll
    for (int i = 0; i < 2; ++i) {
      int g = t + i * 256, r = g >> 3, cg = g & 7;
      int f = (r & 7) ^ ((r >> 3) & 7);
      *(uint4*)&Ks[r * 64 + (((cg ^ f) & 7) << 3)] = kg[i];
      *(uint4*)&Vt[r * 64 + (((cg ^ f) & 7) << 3)] = vg[i];
    }
    __syncthreads();

    // prefetch next KV tile (hides HBM latency under compute)
    if (c0 + 64 < SQ) {
      #pragma unroll
      for (int i = 0; i < 2; ++i) {
        int g = t + i * 256, r = g >> 3, cg = g & 7;
        kg[i] = *(const uint4*)&Kb[(size_t)(c0 + 64 + r) * DK + cg * 8];
        vg[i] = *(const uint4*)&Vb[(size_t)r * SQ + c0 + 64 + cg * 8];
      }
    }

    // QK^T (swapped): s[fr] rows = kk window fr*16.., cols = wave's q window
    f32x4 s[4] = {};
    #pragma unroll
    for (int kw = 0; kw < 2; ++kw) {
      #pragma unroll
      for (int fr = 0; fr < 4; ++fr) {
        bf16x8 kf = *(const bf16x8*)&Ks[swz(fr * 16 + rsel, ko + 32 * kw)];
        s[fr] = __builtin_amdgcn_mfma_f32_16x16x32_bf16(kf, qf[kw], s[fr], 0, 0, 0);
      }
    }

    // online softmax for q-row = rsel (16 scores in-lane across 4 lane-groups)
    float tm = s[0][0];
    #pragma unroll
    for (int fr = 0; fr < 4; ++fr)
      #pragma unroll
      for (int i = 0; i < 4; ++i) tm = fmaxf(tm, s[fr][i]);
    tm = fmaxf(tm, __shfl_xor(tm, 16));
    tm = fmaxf(tm, __shfl_xor(tm, 32));
    const float mnew = fmaxf(m, tm);
    const float corr = __expf((m - mnew) * scale);
    float p[4][4], ps = 0.f;
    #pragma unroll
    for (int fr = 0; fr < 4; ++fr)
      #pragma unroll
      for (int i = 0; i < 4; ++i) {
        p[fr][i] = __expf((s[fr][i] - mnew) * scale);
        ps += p[fr][i];
      }
    ps += __shfl_xor(ps, 16);
    ps += __shfl_xor(ps, 32);
    l = l * corr + ps;
    m = mnew;

    // write P (bf16) to this wave's LDS region: Pl[q=rsel][kk0..kk0+3]
    #pragma unroll
    for (int fr = 0; fr < 4; ++fr) {
      unsigned lo = (unsigned)f2bf(p[fr][0]) | ((unsigned)f2bf(p[fr][1]) << 16);
      unsigned hi = (unsigned)f2bf(p[fr][2]) | ((unsigned)f2bf(p[fr][3]) << 16);
      uint2 pv = {lo, hi};
      const int kk0 = (ln >> 4) * 4 + fr * 16;
      *(uint2*)&Pl[w * 1024 + swz(rsel, kk0)] = pv;
    }

    // rescale O: corr for q_out=(ln>>4)*4+i lives at lane q_out
    float ci[4];
    #pragma unroll
    for (int i = 0; i < 4; ++i) ci[i] = __shfl(corr, (ln >> 4) * 4 + i);
    #pragma unroll
    for (int n = 0; n < 4; ++n)
      #pragma unroll
      for (int i = 0; i < 4; ++i) acc2[n][i] *= ci[i];

    // PV: A = P rows (wave-local), B = Vt rows
    #pragma unroll
    for (int kw = 0; kw < 2; ++kw) {
      bf16x8 pf = *(const bf16x8*)&Pl[w * 1024 + swz(rsel, ko + 32 * kw)];
      #pragma unroll
      for (int n = 0; n < 4; ++n) {
        bf16x8 vf = *(const bf16x8*)&Vt[swz(n * 16 + rsel, ko + 32 * kw)];
        acc2[n] = __builtin_amdgcn_mfma_f32_16x16x32_bf16(pf, vf, acc2[n], 0, 0, 0);
      }
    }
  }

  // epilogue: divide by l (per output row) and store bf16 ctx [B][S][DM]
  const float rl = 1.0f / l;
  float ri[4];
  #pragma unroll
  for (int i = 0; i < 4; ++i) ri[i] = __shfl(rl, (ln >> 4) * 4 + i);
  const int b = bh >> 4, h = bh & 15;
  #pragma unroll
  for (int n = 0; n < 4; ++n)
    #pragma unroll
    for (int i = 0; i < 4; ++i) {
      const int srow = q0 + w * 16 + (ln >> 4) * 4 + i;
      ctx[((size_t)(b * SQ + srow)) * DM + h * 64 + n * 16 + rsel] =
          f2bf(acc2[n][i] * ri[i]);
    }
}

extern "C" void kernel_launch(void* const* d_in, const int* in_sizes, int n_in,
                              void* d_out, int out_size, void* d_ws, size_t ws_size,
                              hipStream_t stream) {
  const float* x  = (const float*)d_in[0];
  const float* Wq = (const float*)d_in[1];
  const float* bq = (const float*)d_in[2];
  const float* Wk = (const float*)d_in[3];
  const float* bk = (const float*)d_in[4];
  const float* Wv = (const float*)d_in[5];
  const float* bv = (const float*)d_in[6];
  const float* Wo = (const float*)d_in[7];
  const float* bo = (const float*)d_in[8];
  float* out = (float*)d_out;

  unsigned short* xb   = (unsigned short*)d_ws;            // [MR,DM] bf16, 8MB
  unsigned short* Wtq  = xb  + (size_t)MR * DM;            // [N,K] bf16, 2MB each
  unsigned short* Wtk  = Wtq + (size_t)DM * DM;
  unsigned short* Wtv  = Wtk + (size_t)DM * DM;
  unsigned short* Wto  = Wtv + (size_t)DM * DM;
  unsigned short* Qb   = Wto + (size_t)DM * DM;            // [B,H,S,DK] bf16, 8MB each
  unsigned short* Kb   = Qb  + (size_t)MR * DM;
  unsigned short* Vb   = Kb  + (size_t)MR * DM;            // [B,H,DK,S] (transposed)
  unsigned short* ctxb = Vb  + (size_t)MR * DM;            // [B,S,DM] bf16, 8MB
  // total 48 MB

  cast_kernel<<<(MR * DM / 8 + 255) / 256, 256, 0, stream>>>(x, xb, MR * DM / 8);
  dim3 tg(DM / 32, DM / 32);
  transpose_cast_kernel<<<tg, 256, 0, stream>>>(Wq, Wtq);
  transpose_cast_kernel<<<tg, 256, 0, stream>>>(Wk, Wtk);
  transpose_cast_kernel<<<tg, 256, 0, stream>>>(Wv, Wtv);
  transpose_cast_kernel<<<tg, 256, 0, stream>>>(Wo, Wto);

  dim3 gg(DM / 64, MR / 128);  // (16, 32) = 512 blocks = 2/CU
  mfma_gemm<1><<<gg, 256, 0, stream>>>(xb, Wtq, bq, Qb);
  mfma_gemm<1><<<gg, 256, 0, stream>>>(xb, Wtk, bk, Kb);
  mfma_gemm<2><<<gg, 256, 0, stream>>>(xb, Wtv, bv, Vb);

  attn_mfma<<<dim3(SQ / 64, BB * NH), 256, 0, stream>>>(Qb, Kb, Vb, ctxb);

  mfma_gemm<0><<<gg, 256, 0, stream>>>(ctxb, Wto, bo, out);
}

// Round 8
// 256.013 us; speedup vs baseline: 1.5540x; 1.5540x over previous
//
#include <hip/hip_runtime.h>
#include <hip/hip_bf16.h>
#include <math.h>

constexpr int DM = 1024;    // d_model
constexpr int NH = 16;      // heads
constexpr int DK = 64;      // head dim
constexpr int SQ = 2048;    // seq len
constexpr int BB = 2;       // batch
constexpr int MR = BB * SQ; // 4096 rows

typedef short bf16x8 __attribute__((ext_vector_type(8)));
typedef float f32x4 __attribute__((ext_vector_type(4)));

__device__ inline unsigned short f2bf(float f) {
  unsigned u = __float_as_uint(f);
  unsigned r = (u + 0x7fffu + ((u >> 16) & 1u)) >> 16;  // RNE
  return (unsigned short)r;
}

// XOR swizzle for [R][64] bf16 LDS tiles. f(r) xors the 16B-granule index.
__device__ inline int fswz(int r) { return (r & 7) ^ ((r >> 3) & 7); }
__device__ inline int swz(int r, int c) {
  return r * 64 + ((((c >> 3) ^ fswz(r)) & 7) << 3) + (c & 7);
}

// -------- cast f32 -> bf16, 8 elems/thread --------
__global__ __launch_bounds__(256)
void cast_kernel(const float* __restrict__ in, unsigned short* __restrict__ out, int n8) {
  int i = blockIdx.x * 256 + threadIdx.x;
  if (i >= n8) return;
  float4 a = *(const float4*)&in[(size_t)i * 8];
  float4 b = *(const float4*)&in[(size_t)i * 8 + 4];
  ushort4 lo = {f2bf(a.x), f2bf(a.y), f2bf(a.z), f2bf(a.w)};
  ushort4 hi = {f2bf(b.x), f2bf(b.y), f2bf(b.z), f2bf(b.w)};
  *(ushort4*)&out[(size_t)i * 8] = lo;
  *(ushort4*)&out[(size_t)i * 8 + 4] = hi;
}

// -------- cast+transpose: W[K][N] f32 -> Wt[N][K] bf16 (32x32 tiles) --------
__global__ __launch_bounds__(256)
void transpose_cast_kernel(const float* __restrict__ W, unsigned short* __restrict__ Wt) {
  __shared__ float tl[32][33];
  const int tx = threadIdx.x & 31, ty = threadIdx.x >> 5;  // 32 x 8
  const int x0 = blockIdx.x * 32, y0 = blockIdx.y * 32;    // x0: n, y0: k
  #pragma unroll
  for (int i = 0; i < 4; ++i)
    tl[ty + i * 8][tx] = W[(size_t)(y0 + ty + i * 8) * DM + x0 + tx];
  __syncthreads();
  #pragma unroll
  for (int i = 0; i < 4; ++i)
    Wt[(size_t)(x0 + ty + i * 8) * DM + y0 + tx] = f2bf(tl[tx][ty + i * 8]);
}

// -------- V transpose: [B,H,S,DK] -> [B,H,DK,S], 64x64 bf16 tiles --------
// Coalesced b128 reads and writes; swizzled LDS (writes uniform, reads 2-way).
__global__ __launch_bounds__(256)
void transpose_v(const unsigned short* __restrict__ V, unsigned short* __restrict__ Vt) {
  __shared__ unsigned short tl[64 * 64];
  const int t = threadIdx.x;
  const int s0 = blockIdx.x * 64, bh = blockIdx.y;
  const unsigned short* src = V + (size_t)bh * SQ * DK;
  unsigned short* dst = Vt + (size_t)bh * DK * SQ;
  #pragma unroll
  for (int i = 0; i < 2; ++i) {
    int g = t + i * 256, r = g >> 3, cg = g & 7;   // r: s-row, cg: d-octet
    uint4 v = *(const uint4*)&src[(size_t)(s0 + r) * DK + cg * 8];
    *(uint4*)&tl[r * 64 + (((cg ^ fswz(r)) & 7) << 3)] = v;
  }
  __syncthreads();
  #pragma unroll
  for (int i = 0; i < 2; ++i) {
    int g = t + i * 256, d = g >> 3, cs = g & 7;   // d: out row, cs: s-octet
    uint4 o;
    unsigned short* op = (unsigned short*)&o;
    #pragma unroll
    for (int e = 0; e < 8; ++e)
      op[e] = tl[swz(cs * 8 + e, d)];
    *(uint4*)&dst[(size_t)d * SQ + s0 + cs * 8] = o;
  }
}

// -------- bf16 MFMA GEMM, 2-phase dbuf pipeline (T3-minimum) --------
// Tile 128x128, BK=64. Staging via global_load_lds(16B): linear LDS dest,
// pre-swizzled per-lane global source; fragment reads use swz() (rule #21).
// MODE 0: out f32 row-major [M,N].  MODE 1: out bf16 remapped [B,H,S,DK].
template<int MODE>
__global__ __launch_bounds__(256)
void mfma_gemm(const unsigned short* __restrict__ A, const unsigned short* __restrict__ Bt,
               const float* __restrict__ bias, void* __restrict__ outp)
{
  constexpr int K = DM, N = DM;
  __shared__ unsigned short As[2][128 * 64];
  __shared__ unsigned short Bs[2][128 * 64];
  const int t = threadIdx.x;
  const int w = t >> 6, ln = t & 63;
  const int wr = w >> 1, wc = w & 1;        // 2x2 wave grid, 64x64 per wave
  const int rb = blockIdx.y * 128, cb = blockIdx.x * 128;

  f32x4 acc[4][4] = {};

  auto stage = [&](int buf, int k0) {
    #pragma unroll
    for (int j = 0; j < 4; ++j) {
      const int rows8 = (w * 4 + j) * 8;            // wave-uniform LDS chunk
      const int r = rows8 + (ln >> 3);              // tile row this lane fetches
      const int gc = (((ln & 7) ^ fswz(r)) & 7) * 8; // inverse-swizzled source col
      __builtin_amdgcn_global_load_lds(
          (const __attribute__((address_space(1))) void*)&A[(size_t)(rb + r) * K + k0 + gc],
          (__attribute__((address_space(3))) void*)&As[buf][rows8 * 64], 16, 0, 0);
      __builtin_amdgcn_global_load_lds(
          (const __attribute__((address_space(1))) void*)&Bt[(size_t)(cb + r) * K + k0 + gc],
          (__attribute__((address_space(3))) void*)&Bs[buf][rows8 * 64], 16, 0, 0);
    }
  };

  stage(0, 0);
  asm volatile("s_waitcnt vmcnt(0)" ::: "memory");
  __builtin_amdgcn_s_barrier();

  for (int it = 0; it < K / 64; ++it) {
    const int buf = it & 1;
    if (it < K / 64 - 1) stage(buf ^ 1, (it + 1) * 64);  // prefetch, drained after compute
    const int rsel = ln & 15;
    #pragma unroll
    for (int kk = 0; kk < 2; ++kk) {
      const int ko = kk * 32 + (ln >> 4) * 8;
      bf16x8 af[4], bfr[4];
      #pragma unroll
      for (int m = 0; m < 4; ++m)
        af[m] = *(const bf16x8*)&As[buf][swz(wr * 64 + m * 16 + rsel, ko)];
      #pragma unroll
      for (int n = 0; n < 4; ++n)
        bfr[n] = *(const bf16x8*)&Bs[buf][swz(wc * 64 + n * 16 + rsel, ko)];
      #pragma unroll
      for (int m = 0; m < 4; ++m)
        #pragma unroll
        for (int n = 0; n < 4; ++n)
          acc[m][n] = __builtin_amdgcn_mfma_f32_16x16x32_bf16(af[m], bfr[n], acc[m][n], 0, 0, 0);
    }
    asm volatile("s_waitcnt vmcnt(0)" ::: "memory");  // prefetch landed (hidden under MFMA)
    __builtin_amdgcn_s_barrier();
  }

  // epilogue: C/D layout col = ln&15, row = (ln>>4)*4 + i
  const int cl = ln & 15, rg = (ln >> 4) * 4;
  #pragma unroll
  for (int m = 0; m < 4; ++m) {
    #pragma unroll
    for (int i = 0; i < 4; ++i) {
      const int r = rb + wr * 64 + m * 16 + rg + i;
      #pragma unroll
      for (int n = 0; n < 4; ++n) {
        const int c = cb + wc * 64 + n * 16 + cl;
        const float v = acc[m][n][i] + bias[c];
        if (MODE == 0) {
          ((float*)outp)[(size_t)r * N + c] = v;
        } else {
          const int b = r >> 11, s = r & 2047;  // r = b*2048 + s
          const int h = c >> 6, d = c & 63;     // c = h*64 + d
          ((unsigned short*)outp)[(((size_t)(b * NH + h)) * SQ + s) * DK + d] = f2bf(v);
        }
      }
    }
  }
}

// -------- MFMA flash attention (unchanged from round 7) --------
__global__ __launch_bounds__(256)
void attn_mfma(const unsigned short* __restrict__ Qp, const unsigned short* __restrict__ Kp,
               const unsigned short* __restrict__ Vp, unsigned short* __restrict__ ctx)
{
  __shared__ unsigned short Qs[64 * 64];
  __shared__ unsigned short Ks[64 * 64];
  __shared__ unsigned short Vt[64 * 64];      // V^T: [d][kv]
  __shared__ unsigned short Pl[4 * 16 * 64];  // per-wave P: [q][kk]
  const int t = threadIdx.x, w = t >> 6, ln = t & 63;
  const int bh = blockIdx.y, q0 = blockIdx.x * 64;
  const float scale = 0.125f;  // 1/sqrt(64), folded into exp args
  const unsigned short* Qb = Qp + (size_t)bh * SQ * DK;
  const unsigned short* Kb = Kp + (size_t)bh * SQ * DK;
  const unsigned short* Vb = Vp + (size_t)bh * DK * SQ;  // [DK][SQ]

  #pragma unroll
  for (int i = 0; i < 2; ++i) {
    int g = t + i * 256, r = g >> 3, cg = g & 7;
    uint4 qv = *(const uint4*)&Qb[(size_t)(q0 + r) * DK + cg * 8];
    *(uint4*)&Qs[r * 64 + (((cg ^ fswz(r)) & 7) << 3)] = qv;
  }
  __syncthreads();
  const int rsel = ln & 15, ko = (ln >> 4) * 8;
  bf16x8 qf[2];
  qf[0] = *(const bf16x8*)&Qs[swz(w * 16 + rsel, ko)];
  qf[1] = *(const bf16x8*)&Qs[swz(w * 16 + rsel, ko + 32)];

  f32x4 acc2[4] = {};          // O accum: O[q=(ln>>4)*4+i][d=16n+rsel]
  float m = -1e30f, l = 0.f;   // per-lane state for q-row = rsel

  uint4 kg[2], vg[2];
  #pragma unroll
  for (int i = 0; i < 2; ++i) {
    int g = t + i * 256, r = g >> 3, cg = g & 7;
    kg[i] = *(const uint4*)&Kb[(size_t)r * DK + cg * 8];
    vg[i] = *(const uint4*)&Vb[(size_t)r * SQ + cg * 8];
  }

  for (int c0 = 0; c0 < SQ; c0 += 64) {
    __syncthreads();
    #pragma unroll
    for (int i = 0; i < 2; ++i) {
      int g = t + i * 256, r = g >> 3, cg = g & 7;
      *(uint4*)&Ks[r * 64 + (((cg ^ fswz(r)) & 7) << 3)] = kg[i];
      *(uint4*)&Vt[r * 64 + (((cg ^ fswz(r)) & 7) << 3)] = vg[i];
    }
    __syncthreads();

    if (c0 + 64 < SQ) {
      #pragma unroll
      for (int i = 0; i < 2; ++i) {
        int g = t + i * 256, r = g >> 3, cg = g & 7;
        kg[i] = *(const uint4*)&Kb[(size_t)(c0 + 64 + r) * DK + cg * 8];
        vg[i] = *(const uint4*)&Vb[(size_t)r * SQ + c0 + 64 + cg * 8];
      }
    }

    f32x4 s[4] = {};
    #pragma unroll
    for (int kw = 0; kw < 2; ++kw) {
      #pragma unroll
      for (int fr = 0; fr < 4; ++fr) {
        bf16x8 kf = *(const bf16x8*)&Ks[swz(fr * 16 + rsel, ko + 32 * kw)];
        s[fr] = __builtin_amdgcn_mfma_f32_16x16x32_bf16(kf, qf[kw], s[fr], 0, 0, 0);
      }
    }

    float tm = s[0][0];
    #pragma unroll
    for (int fr = 0; fr < 4; ++fr)
      #pragma unroll
      for (int i = 0; i < 4; ++i) tm = fmaxf(tm, s[fr][i]);
    tm = fmaxf(tm, __shfl_xor(tm, 16));
    tm = fmaxf(tm, __shfl_xor(tm, 32));
    const float mnew = fmaxf(m, tm);
    const float corr = __expf((m - mnew) * scale);
    float p[4][4], ps = 0.f;
    #pragma unroll
    for (int fr = 0; fr < 4; ++fr)
      #pragma unroll
      for (int i = 0; i < 4; ++i) {
        p[fr][i] = __expf((s[fr][i] - mnew) * scale);
        ps += p[fr][i];
      }
    ps += __shfl_xor(ps, 16);
    ps += __shfl_xor(ps, 32);
    l = l * corr + ps;
    m = mnew;

    #pragma unroll
    for (int fr = 0; fr < 4; ++fr) {
      unsigned lo = (unsigned)f2bf(p[fr][0]) | ((unsigned)f2bf(p[fr][1]) << 16);
      unsigned hi = (unsigned)f2bf(p[fr][2]) | ((unsigned)f2bf(p[fr][3]) << 16);
      uint2 pv = {lo, hi};
      const int kk0 = (ln >> 4) * 4 + fr * 16;
      *(uint2*)&Pl[w * 1024 + swz(rsel, kk0)] = pv;
    }

    float ci[4];
    #pragma unroll
    for (int i = 0; i < 4; ++i) ci[i] = __shfl(corr, (ln >> 4) * 4 + i);
    #pragma unroll
    for (int n = 0; n < 4; ++n)
      #pragma unroll
      for (int i = 0; i < 4; ++i) acc2[n][i] *= ci[i];

    #pragma unroll
    for (int kw = 0; kw < 2; ++kw) {
      bf16x8 pf = *(const bf16x8*)&Pl[w * 1024 + swz(rsel, ko + 32 * kw)];
      #pragma unroll
      for (int n = 0; n < 4; ++n) {
        bf16x8 vf = *(const bf16x8*)&Vt[swz(n * 16 + rsel, ko + 32 * kw)];
        acc2[n] = __builtin_amdgcn_mfma_f32_16x16x32_bf16(pf, vf, acc2[n], 0, 0, 0);
      }
    }
  }

  const float rl = 1.0f / l;
  float ri[4];
  #pragma unroll
  for (int i = 0; i < 4; ++i) ri[i] = __shfl(rl, (ln >> 4) * 4 + i);
  const int b = bh >> 4, h = bh & 15;
  #pragma unroll
  for (int n = 0; n < 4; ++n)
    #pragma unroll
    for (int i = 0; i < 4; ++i) {
      const int srow = q0 + w * 16 + (ln >> 4) * 4 + i;
      ctx[((size_t)(b * SQ + srow)) * DM + h * 64 + n * 16 + rsel] =
          f2bf(acc2[n][i] * ri[i]);
    }
}

extern "C" void kernel_launch(void* const* d_in, const int* in_sizes, int n_in,
                              void* d_out, int out_size, void* d_ws, size_t ws_size,
                              hipStream_t stream) {
  const float* x  = (const float*)d_in[0];
  const float* Wq = (const float*)d_in[1];
  const float* bq = (const float*)d_in[2];
  const float* Wk = (const float*)d_in[3];
  const float* bk = (const float*)d_in[4];
  const float* Wv = (const float*)d_in[5];
  const float* bv = (const float*)d_in[6];
  const float* Wo = (const float*)d_in[7];
  const float* bo = (const float*)d_in[8];
  float* out = (float*)d_out;

  unsigned short* xb   = (unsigned short*)d_ws;            // [MR,DM] bf16, 8MB
  unsigned short* Wtq  = xb  + (size_t)MR * DM;            // [N,K] bf16, 2MB each
  unsigned short* Wtk  = Wtq + (size_t)DM * DM;
  unsigned short* Wtv  = Wtk + (size_t)DM * DM;
  unsigned short* Wto  = Wtv + (size_t)DM * DM;
  unsigned short* Qb   = Wto + (size_t)DM * DM;            // [B,H,S,DK] bf16, 8MB each
  unsigned short* Kb   = Qb  + (size_t)MR * DM;
  unsigned short* Vb   = Kb  + (size_t)MR * DM;            // [B,H,S,DK]
  unsigned short* Vtb  = Vb  + (size_t)MR * DM;            // [B,H,DK,S] 8MB
  unsigned short* ctxb = Vtb + (size_t)MR * DM;            // [B,S,DM] bf16, 8MB
  // total 56 MB

  cast_kernel<<<(MR * DM / 8 + 255) / 256, 256, 0, stream>>>(x, xb, MR * DM / 8);
  dim3 tg(DM / 32, DM / 32);
  transpose_cast_kernel<<<tg, 256, 0, stream>>>(Wq, Wtq);
  transpose_cast_kernel<<<tg, 256, 0, stream>>>(Wk, Wtk);
  transpose_cast_kernel<<<tg, 256, 0, stream>>>(Wv, Wtv);
  transpose_cast_kernel<<<tg, 256, 0, stream>>>(Wo, Wto);

  dim3 gg(DM / 128, MR / 128);  // (8, 32) = 256 blocks
  mfma_gemm<1><<<gg, 256, 0, stream>>>(xb, Wtq, bq, Qb);
  mfma_gemm<1><<<gg, 256, 0, stream>>>(xb, Wtk, bk, Kb);
  mfma_gemm<1><<<gg, 256, 0, stream>>>(xb, Wtv, bv, Vb);
  transpose_v<<<dim3(SQ / 64, BB * NH), 256, 0, stream>>>(Vb, Vtb);

  attn_mfma<<<dim3(SQ / 64, BB * NH), 256, 0, stream>>>(Qb, Kb, Vtb, ctxb);

  mfma_gemm<0><<<gg, 256, 0, stream>>>(ctxb, Wto, bo, out);
}

// Round 9
// 200.688 us; speedup vs baseline: 1.9825x; 1.2757x over previous
//
#include <hip/hip_runtime.h>
#include <hip/hip_bf16.h>
#include <math.h>

constexpr int DM = 1024;    // d_model
constexpr int NH = 16;      // heads
constexpr int DK = 64;      // head dim
constexpr int SQ = 2048;    // seq len
constexpr int BB = 2;       // batch
constexpr int MR = BB * SQ; // 4096 rows

typedef short bf16x8 __attribute__((ext_vector_type(8)));
typedef float f32x4 __attribute__((ext_vector_type(4)));

__device__ inline unsigned short f2bf(float f) {
  unsigned u = __float_as_uint(f);
  unsigned r = (u + 0x7fffu + ((u >> 16) & 1u)) >> 16;  // RNE
  return (unsigned short)r;
}

// XOR swizzle for [R][64] bf16 LDS tiles. f(r) xors the 16B-granule index.
__device__ inline int fswz(int r) { return (r & 7) ^ ((r >> 3) & 7); }
__device__ inline int swz(int r, int c) {
  return r * 64 + ((((c >> 3) ^ fswz(r)) & 7) << 3) + (c & 7);
}

// -------- cast f32 -> bf16, 8 elems/thread --------
__global__ __launch_bounds__(256)
void cast_kernel(const float* __restrict__ in, unsigned short* __restrict__ out, int n8) {
  int i = blockIdx.x * 256 + threadIdx.x;
  if (i >= n8) return;
  float4 a = *(const float4*)&in[(size_t)i * 8];
  float4 b = *(const float4*)&in[(size_t)i * 8 + 4];
  ushort4 lo = {f2bf(a.x), f2bf(a.y), f2bf(a.z), f2bf(a.w)};
  ushort4 hi = {f2bf(b.x), f2bf(b.y), f2bf(b.z), f2bf(b.w)};
  *(ushort4*)&out[(size_t)i * 8] = lo;
  *(ushort4*)&out[(size_t)i * 8 + 4] = hi;
}

// -------- cast+transpose: W[K][N] f32 -> Wt[N][K] bf16 (32x32 tiles) --------
__global__ __launch_bounds__(256)
void transpose_cast_kernel(const float* __restrict__ W, unsigned short* __restrict__ Wt) {
  __shared__ float tl[32][33];
  const int tx = threadIdx.x & 31, ty = threadIdx.x >> 5;  // 32 x 8
  const int x0 = blockIdx.x * 32, y0 = blockIdx.y * 32;    // x0: n, y0: k
  #pragma unroll
  for (int i = 0; i < 4; ++i)
    tl[ty + i * 8][tx] = W[(size_t)(y0 + ty + i * 8) * DM + x0 + tx];
  __syncthreads();
  #pragma unroll
  for (int i = 0; i < 4; ++i)
    Wt[(size_t)(x0 + ty + i * 8) * DM + y0 + tx] = f2bf(tl[tx][ty + i * 8]);
}

// -------- bf16 MFMA GEMM, 2-phase dbuf pipeline (round-8, unchanged) --------
template<int MODE>
__global__ __launch_bounds__(256)
void mfma_gemm(const unsigned short* __restrict__ A, const unsigned short* __restrict__ Bt,
               const float* __restrict__ bias, void* __restrict__ outp)
{
  constexpr int K = DM, N = DM;
  __shared__ unsigned short As[2][128 * 64];
  __shared__ unsigned short Bs[2][128 * 64];
  const int t = threadIdx.x;
  const int w = t >> 6, ln = t & 63;
  const int wr = w >> 1, wc = w & 1;        // 2x2 wave grid, 64x64 per wave
  const int rb = blockIdx.y * 128, cb = blockIdx.x * 128;

  f32x4 acc[4][4] = {};

  auto stage = [&](int buf, int k0) {
    #pragma unroll
    for (int j = 0; j < 4; ++j) {
      const int rows8 = (w * 4 + j) * 8;            // wave-uniform LDS chunk
      const int r = rows8 + (ln >> 3);              // tile row this lane fetches
      const int gc = (((ln & 7) ^ fswz(r)) & 7) * 8; // inverse-swizzled source col
      __builtin_amdgcn_global_load_lds(
          (const __attribute__((address_space(1))) void*)&A[(size_t)(rb + r) * K + k0 + gc],
          (__attribute__((address_space(3))) void*)&As[buf][rows8 * 64], 16, 0, 0);
      __builtin_amdgcn_global_load_lds(
          (const __attribute__((address_space(1))) void*)&Bt[(size_t)(cb + r) * K + k0 + gc],
          (__attribute__((address_space(3))) void*)&Bs[buf][rows8 * 64], 16, 0, 0);
    }
  };

  stage(0, 0);
  asm volatile("s_waitcnt vmcnt(0)" ::: "memory");
  __builtin_amdgcn_s_barrier();

  for (int it = 0; it < K / 64; ++it) {
    const int buf = it & 1;
    if (it < K / 64 - 1) stage(buf ^ 1, (it + 1) * 64);  // prefetch, drained after compute
    const int rsel = ln & 15;
    #pragma unroll
    for (int kk = 0; kk < 2; ++kk) {
      const int ko = kk * 32 + (ln >> 4) * 8;
      bf16x8 af[4], bfr[4];
      #pragma unroll
      for (int m = 0; m < 4; ++m)
        af[m] = *(const bf16x8*)&As[buf][swz(wr * 64 + m * 16 + rsel, ko)];
      #pragma unroll
      for (int n = 0; n < 4; ++n)
        bfr[n] = *(const bf16x8*)&Bs[buf][swz(wc * 64 + n * 16 + rsel, ko)];
      #pragma unroll
      for (int m = 0; m < 4; ++m)
        #pragma unroll
        for (int n = 0; n < 4; ++n)
          acc[m][n] = __builtin_amdgcn_mfma_f32_16x16x32_bf16(af[m], bfr[n], acc[m][n], 0, 0, 0);
    }
    asm volatile("s_waitcnt vmcnt(0)" ::: "memory");  // prefetch landed (hidden under MFMA)
    __builtin_amdgcn_s_barrier();
  }

  // epilogue: C/D layout col = ln&15, row = (ln>>4)*4 + i
  const int cl = ln & 15, rg = (ln >> 4) * 4;
  #pragma unroll
  for (int m = 0; m < 4; ++m) {
    #pragma unroll
    for (int i = 0; i < 4; ++i) {
      const int r = rb + wr * 64 + m * 16 + rg + i;
      #pragma unroll
      for (int n = 0; n < 4; ++n) {
        const int c = cb + wc * 64 + n * 16 + cl;
        const float v = acc[m][n][i] + bias[c];
        if (MODE == 0) {
          ((float*)outp)[(size_t)r * N + c] = v;
        } else {
          const int b = r >> 11, s = r & 2047;  // r = b*2048 + s
          const int h = c >> 6, d = c & 63;     // c = h*64 + d
          ((unsigned short*)outp)[(((size_t)(b * NH + h)) * SQ + s) * DK + d] = f2bf(v);
        }
      }
    }
  }
}

// -------- MFMA flash attention, QBLK=128 (2 q-windows per wave) --------
// Round-6 V path (V [B,H,S,DK], in-kernel transpose at stage); K/V fragments
// loaded once per tile and reused by both q-windows.
__global__ __launch_bounds__(256)
void attn_mfma(const unsigned short* __restrict__ Qp, const unsigned short* __restrict__ Kp,
               const unsigned short* __restrict__ Vp, unsigned short* __restrict__ ctx)
{
  __shared__ unsigned short Qs[128 * 64];     // 16KB
  __shared__ unsigned short Ks[64 * 64];      // 8KB
  __shared__ unsigned short Vt[64 * 64];      // 8KB  V^T: [d][kv]
  __shared__ unsigned short Pl[4 * 16 * 64];  // 8KB  per-wave P: [q][kk]
  const int t = threadIdx.x, w = t >> 6, ln = t & 63;
  const int bh = blockIdx.y, q0 = blockIdx.x * 128;
  const float scale = 0.125f;  // 1/sqrt(64), folded into exp args
  const unsigned short* Qb = Qp + (size_t)bh * SQ * DK;
  const unsigned short* Kb = Kp + (size_t)bh * SQ * DK;
  const unsigned short* Vb = Vp + (size_t)bh * SQ * DK;

  // stage Q tile: 128 rows x 64 = 1024 granules, 4/thread
  #pragma unroll
  for (int i = 0; i < 4; ++i) {
    int g = t + i * 256, r = g >> 3, cg = g & 7;
    uint4 qv = *(const uint4*)&Qb[(size_t)(q0 + r) * DK + cg * 8];
    *(uint4*)&Qs[r * 64 + (((cg ^ fswz(r)) & 7) << 3)] = qv;
  }
  __syncthreads();
  const int rsel = ln & 15, ko = (ln >> 4) * 8;
  bf16x8 qf[2][2];
  #pragma unroll
  for (int win = 0; win < 2; ++win)
    #pragma unroll
    for (int kw = 0; kw < 2; ++kw)
      qf[win][kw] = *(const bf16x8*)&Qs[swz(w * 32 + win * 16 + rsel, ko + 32 * kw)];

  f32x4 acc2[2][4] = {};                 // O[q=(ln>>4)*4+i][d=16n+rsel] per window
  float mm[2] = {-1e30f, -1e30f}, ll[2] = {0.f, 0.f};

  uint4 kg[2], vg[2];
  #pragma unroll
  for (int i = 0; i < 2; ++i) {
    int g = t + i * 256, r = g >> 3, cg = g & 7;
    kg[i] = *(const uint4*)&Kb[(size_t)r * DK + cg * 8];
    vg[i] = *(const uint4*)&Vb[(size_t)r * DK + cg * 8];
  }

  for (int c0 = 0; c0 < SQ; c0 += 64) {
    __syncthreads();  // previous tile's Ks/Vt reads done
    #pragma unroll
    for (int i = 0; i < 2; ++i) {
      int g = t + i * 256, r = g >> 3, cg = g & 7;
      *(uint4*)&Ks[r * 64 + (((cg ^ fswz(r)) & 7) << 3)] = kg[i];
      const unsigned short* vv = (const unsigned short*)&vg[i];
      const int d0 = cg * 8;
      #pragma unroll
      for (int e = 0; e < 8; ++e)
        Vt[swz(d0 + e, r)] = vv[e];   // transpose write
    }
    __syncthreads();

    // prefetch next KV tile (hides HBM latency under compute)
    if (c0 + 64 < SQ) {
      #pragma unroll
      for (int i = 0; i < 2; ++i) {
        int g = t + i * 256, r = g >> 3, cg = g & 7;
        kg[i] = *(const uint4*)&Kb[(size_t)(c0 + 64 + r) * DK + cg * 8];
        vg[i] = *(const uint4*)&Vb[(size_t)(c0 + 64 + r) * DK + cg * 8];
      }
    }

    // fragment loads, shared by both q-windows
    bf16x8 kf[2][4], vf[2][4];
    #pragma unroll
    for (int kw = 0; kw < 2; ++kw)
      #pragma unroll
      for (int fr = 0; fr < 4; ++fr)
        kf[kw][fr] = *(const bf16x8*)&Ks[swz(fr * 16 + rsel, ko + 32 * kw)];
    #pragma unroll
    for (int kw = 0; kw < 2; ++kw)
      #pragma unroll
      for (int n = 0; n < 4; ++n)
        vf[kw][n] = *(const bf16x8*)&Vt[swz(n * 16 + rsel, ko + 32 * kw)];

    #pragma unroll
    for (int win = 0; win < 2; ++win) {
      // QK^T (swapped): lane holds S[kv=fr*16+(ln>>4)*4+i][q=rsel]
      f32x4 s[4] = {};
      #pragma unroll
      for (int kw = 0; kw < 2; ++kw)
        #pragma unroll
        for (int fr = 0; fr < 4; ++fr)
          s[fr] = __builtin_amdgcn_mfma_f32_16x16x32_bf16(kf[kw][fr], qf[win][kw], s[fr], 0, 0, 0);

      // online softmax for q-row = rsel
      float tm = s[0][0];
      #pragma unroll
      for (int fr = 0; fr < 4; ++fr)
        #pragma unroll
        for (int i = 0; i < 4; ++i) tm = fmaxf(tm, s[fr][i]);
      tm = fmaxf(tm, __shfl_xor(tm, 16));
      tm = fmaxf(tm, __shfl_xor(tm, 32));
      const float mnew = fmaxf(mm[win], tm);
      const float corr = __expf((mm[win] - mnew) * scale);
      float p[4][4], ps = 0.f;
      #pragma unroll
      for (int fr = 0; fr < 4; ++fr)
        #pragma unroll
        for (int i = 0; i < 4; ++i) {
          p[fr][i] = __expf((s[fr][i] - mnew) * scale);
          ps += p[fr][i];
        }
      ps += __shfl_xor(ps, 16);
      ps += __shfl_xor(ps, 32);
      ll[win] = ll[win] * corr + ps;
      mm[win] = mnew;

      // write P (bf16) to this wave's LDS region
      #pragma unroll
      for (int fr = 0; fr < 4; ++fr) {
        unsigned lo = (unsigned)f2bf(p[fr][0]) | ((unsigned)f2bf(p[fr][1]) << 16);
        unsigned hi = (unsigned)f2bf(p[fr][2]) | ((unsigned)f2bf(p[fr][3]) << 16);
        uint2 pv = {lo, hi};
        const int kk0 = (ln >> 4) * 4 + fr * 16;
        *(uint2*)&Pl[w * 1024 + swz(rsel, kk0)] = pv;
      }

      // rescale O: corr for q_out=(ln>>4)*4+i lives at lane q_out
      float ci[4];
      #pragma unroll
      for (int i = 0; i < 4; ++i) ci[i] = __shfl(corr, (ln >> 4) * 4 + i);
      #pragma unroll
      for (int n = 0; n < 4; ++n)
        #pragma unroll
        for (int i = 0; i < 4; ++i) acc2[win][n][i] *= ci[i];

      // PV
      #pragma unroll
      for (int kw = 0; kw < 2; ++kw) {
        bf16x8 pf = *(const bf16x8*)&Pl[w * 1024 + swz(rsel, ko + 32 * kw)];
        #pragma unroll
        for (int n = 0; n < 4; ++n)
          acc2[win][n] = __builtin_amdgcn_mfma_f32_16x16x32_bf16(pf, vf[kw][n], acc2[win][n], 0, 0, 0);
      }
    }
  }

  // epilogue
  const int b = bh >> 4, h = bh & 15;
  #pragma unroll
  for (int win = 0; win < 2; ++win) {
    const float rl = 1.0f / ll[win];
    float ri[4];
    #pragma unroll
    for (int i = 0; i < 4; ++i) ri[i] = __shfl(rl, (ln >> 4) * 4 + i);
    #pragma unroll
    for (int n = 0; n < 4; ++n)
      #pragma unroll
      for (int i = 0; i < 4; ++i) {
        const int srow = q0 + w * 32 + win * 16 + (ln >> 4) * 4 + i;
        ctx[((size_t)(b * SQ + srow)) * DM + h * 64 + n * 16 + rsel] =
            f2bf(acc2[win][n][i] * ri[i]);
      }
  }
}

extern "C" void kernel_launch(void* const* d_in, const int* in_sizes, int n_in,
                              void* d_out, int out_size, void* d_ws, size_t ws_size,
                              hipStream_t stream) {
  const float* x  = (const float*)d_in[0];
  const float* Wq = (const float*)d_in[1];
  const float* bq = (const float*)d_in[2];
  const float* Wk = (const float*)d_in[3];
  const float* bk = (const float*)d_in[4];
  const float* Wv = (const float*)d_in[5];
  const float* bv = (const float*)d_in[6];
  const float* Wo = (const float*)d_in[7];
  const float* bo = (const float*)d_in[8];
  float* out = (float*)d_out;

  unsigned short* xb   = (unsigned short*)d_ws;            // [MR,DM] bf16, 8MB
  unsigned short* Wtq  = xb  + (size_t)MR * DM;            // [N,K] bf16, 2MB each
  unsigned short* Wtk  = Wtq + (size_t)DM * DM;
  unsigned short* Wtv  = Wtk + (size_t)DM * DM;
  unsigned short* Wto  = Wtv + (size_t)DM * DM;
  unsigned short* Qb   = Wto + (size_t)DM * DM;            // [B,H,S,DK] bf16, 8MB each
  unsigned short* Kb   = Qb  + (size_t)MR * DM;
  unsigned short* Vb   = Kb  + (size_t)MR * DM;
  unsigned short* ctxb = Vb  + (size_t)MR * DM;            // [B,S,DM] bf16, 8MB
  // total 48 MB

  cast_kernel<<<(MR * DM / 8 + 255) / 256, 256, 0, stream>>>(x, xb, MR * DM / 8);
  dim3 tg(DM / 32, DM / 32);
  transpose_cast_kernel<<<tg, 256, 0, stream>>>(Wq, Wtq);
  transpose_cast_kernel<<<tg, 256, 0, stream>>>(Wk, Wtk);
  transpose_cast_kernel<<<tg, 256, 0, stream>>>(Wv, Wtv);
  transpose_cast_kernel<<<tg, 256, 0, stream>>>(Wo, Wto);

  dim3 gg(DM / 128, MR / 128);  // (8, 32) = 256 blocks
  mfma_gemm<1><<<gg, 256, 0, stream>>>(xb, Wtq, bq, Qb);
  mfma_gemm<1><<<gg, 256, 0, stream>>>(xb, Wtk, bk, Kb);
  mfma_gemm<1><<<gg, 256, 0, stream>>>(xb, Wtv, bv, Vb);

  attn_mfma<<<dim3(SQ / 128, BB * NH), 256, 0, stream>>>(Qb, Kb, Vb, ctxb);

  mfma_gemm<0><<<gg, 256, 0, stream>>>(ctxb, Wto, bo, out);
}

// Round 10
// 176.228 us; speedup vs baseline: 2.2576x; 1.1388x over previous
//
#include <hip/hip_runtime.h>
#include <hip/hip_bf16.h>
#include <math.h>

constexpr int DM = 1024;    // d_model
constexpr int NH = 16;      // heads
constexpr int DK = 64;      // head dim
constexpr int SQ = 2048;    // seq len
constexpr int BB = 2;       // batch
constexpr int MR = BB * SQ; // 4096 rows

typedef short bf16x8 __attribute__((ext_vector_type(8)));
typedef float f32x4 __attribute__((ext_vector_type(4)));

__device__ inline unsigned short f2bf(float f) {
  unsigned u = __float_as_uint(f);
  unsigned r = (u + 0x7fffu + ((u >> 16) & 1u)) >> 16;  // RNE
  return (unsigned short)r;
}

// XOR swizzle for [R][64] bf16 LDS tiles. f(r) xors the 16B-granule index.
__device__ inline int fswz(int r) { return (r & 7) ^ ((r >> 3) & 7); }
__device__ inline int swz(int r, int c) {
  return r * 64 + ((((c >> 3) ^ fswz(r)) & 7) << 3) + (c & 7);
}

// -------- cast f32 -> bf16, 8 elems/thread --------
__global__ __launch_bounds__(256)
void cast_kernel(const float* __restrict__ in, unsigned short* __restrict__ out, int n8) {
  int i = blockIdx.x * 256 + threadIdx.x;
  if (i >= n8) return;
  float4 a = *(const float4*)&in[(size_t)i * 8];
  float4 b = *(const float4*)&in[(size_t)i * 8 + 4];
  ushort4 lo = {f2bf(a.x), f2bf(a.y), f2bf(a.z), f2bf(a.w)};
  ushort4 hi = {f2bf(b.x), f2bf(b.y), f2bf(b.z), f2bf(b.w)};
  *(ushort4*)&out[(size_t)i * 8] = lo;
  *(ushort4*)&out[(size_t)i * 8 + 4] = hi;
}

// -------- cast+transpose: W[K][N] f32 -> Wt[N][K] bf16 (32x32 tiles) --------
__global__ __launch_bounds__(256)
void transpose_cast_kernel(const float* __restrict__ W, unsigned short* __restrict__ Wt) {
  __shared__ float tl[32][33];
  const int tx = threadIdx.x & 31, ty = threadIdx.x >> 5;  // 32 x 8
  const int x0 = blockIdx.x * 32, y0 = blockIdx.y * 32;    // x0: n, y0: k
  #pragma unroll
  for (int i = 0; i < 4; ++i)
    tl[ty + i * 8][tx] = W[(size_t)(y0 + ty + i * 8) * DM + x0 + tx];
  __syncthreads();
  #pragma unroll
  for (int i = 0; i < 4; ++i)
    Wt[(size_t)(x0 + ty + i * 8) * DM + y0 + tx] = f2bf(tl[tx][ty + i * 8]);
}

// -------- bf16 MFMA GEMM, 2-phase dbuf pipeline --------
// MODE 0: out f32 row-major [M,N].  MODE 1: out bf16 [B,H,S,DK].
// MODE 3: like 1 but scaled by 1/sqrt(DK) (Q projection; softmax scale folded).
template<int MODE>
__global__ __launch_bounds__(256)
void mfma_gemm(const unsigned short* __restrict__ A, const unsigned short* __restrict__ Bt,
               const float* __restrict__ bias, void* __restrict__ outp)
{
  constexpr int K = DM, N = DM;
  __shared__ unsigned short As[2][128 * 64];
  __shared__ unsigned short Bs[2][128 * 64];
  const int t = threadIdx.x;
  const int w = t >> 6, ln = t & 63;
  const int wr = w >> 1, wc = w & 1;        // 2x2 wave grid, 64x64 per wave
  const int rb = blockIdx.y * 128, cb = blockIdx.x * 128;

  f32x4 acc[4][4] = {};

  auto stage = [&](int buf, int k0) {
    #pragma unroll
    for (int j = 0; j < 4; ++j) {
      const int rows8 = (w * 4 + j) * 8;            // wave-uniform LDS chunk
      const int r = rows8 + (ln >> 3);              // tile row this lane fetches
      const int gc = (((ln & 7) ^ fswz(r)) & 7) * 8; // inverse-swizzled source col
      __builtin_amdgcn_global_load_lds(
          (const __attribute__((address_space(1))) void*)&A[(size_t)(rb + r) * K + k0 + gc],
          (__attribute__((address_space(3))) void*)&As[buf][rows8 * 64], 16, 0, 0);
      __builtin_amdgcn_global_load_lds(
          (const __attribute__((address_space(1))) void*)&Bt[(size_t)(cb + r) * K + k0 + gc],
          (__attribute__((address_space(3))) void*)&Bs[buf][rows8 * 64], 16, 0, 0);
    }
  };

  stage(0, 0);
  asm volatile("s_waitcnt vmcnt(0)" ::: "memory");
  __builtin_amdgcn_s_barrier();

  for (int it = 0; it < K / 64; ++it) {
    const int buf = it & 1;
    if (it < K / 64 - 1) stage(buf ^ 1, (it + 1) * 64);  // prefetch, drained after compute
    const int rsel = ln & 15;
    #pragma unroll
    for (int kk = 0; kk < 2; ++kk) {
      const int ko = kk * 32 + (ln >> 4) * 8;
      bf16x8 af[4], bfr[4];
      #pragma unroll
      for (int m = 0; m < 4; ++m)
        af[m] = *(const bf16x8*)&As[buf][swz(wr * 64 + m * 16 + rsel, ko)];
      #pragma unroll
      for (int n = 0; n < 4; ++n)
        bfr[n] = *(const bf16x8*)&Bs[buf][swz(wc * 64 + n * 16 + rsel, ko)];
      #pragma unroll
      for (int m = 0; m < 4; ++m)
        #pragma unroll
        for (int n = 0; n < 4; ++n)
          acc[m][n] = __builtin_amdgcn_mfma_f32_16x16x32_bf16(af[m], bfr[n], acc[m][n], 0, 0, 0);
    }
    asm volatile("s_waitcnt vmcnt(0)" ::: "memory");  // prefetch landed (hidden under MFMA)
    __builtin_amdgcn_s_barrier();
  }

  // epilogue: C/D layout col = ln&15, row = (ln>>4)*4 + i
  const int cl = ln & 15, rg = (ln >> 4) * 4;
  #pragma unroll
  for (int m = 0; m < 4; ++m) {
    #pragma unroll
    for (int i = 0; i < 4; ++i) {
      const int r = rb + wr * 64 + m * 16 + rg + i;
      #pragma unroll
      for (int n = 0; n < 4; ++n) {
        const int c = cb + wc * 64 + n * 16 + cl;
        float v = acc[m][n][i] + bias[c];
        if (MODE == 3) v *= 0.125f;               // fold softmax scale into Q
        if (MODE == 0) {
          ((float*)outp)[(size_t)r * N + c] = v;
        } else {
          const int b = r >> 11, s = r & 2047;  // r = b*2048 + s
          const int h = c >> 6, d = c & 63;     // c = h*64 + d
          ((unsigned short*)outp)[(((size_t)(b * NH + h)) * SQ + s) * DK + d] = f2bf(v);
        }
      }
    }
  }
}

// -------- MFMA flash attention: 8 waves, QBLK=128 (1 q-window/wave) --------
// Q pre-scaled by 1/8 in the projection. Defer-max (THR=8), cvt_pk P pack.
__global__ __launch_bounds__(512, 4)
void attn_mfma(const unsigned short* __restrict__ Qp, const unsigned short* __restrict__ Kp,
               const unsigned short* __restrict__ Vp, unsigned short* __restrict__ ctx)
{
  __shared__ unsigned short Qs[128 * 64];     // 16KB
  __shared__ unsigned short Ks[64 * 64];      // 8KB
  __shared__ unsigned short Vt[64 * 64];      // 8KB  V^T: [d][kv]
  __shared__ unsigned short Pl[8 * 16 * 64];  // 16KB per-wave P: [q][kk]
  const int t = threadIdx.x, w = t >> 6, ln = t & 63;
  const int bh = blockIdx.y, q0 = blockIdx.x * 128;
  const unsigned short* Qb = Qp + (size_t)bh * SQ * DK;
  const unsigned short* Kb = Kp + (size_t)bh * SQ * DK;
  const unsigned short* Vb = Vp + (size_t)bh * SQ * DK;

  // stage Q tile: 128 rows x 64 = 1024 granules, 2/thread (512 threads)
  #pragma unroll
  for (int i = 0; i < 2; ++i) {
    int g = t + i * 512, r = g >> 3, cg = g & 7;
    uint4 qv = *(const uint4*)&Qb[(size_t)(q0 + r) * DK + cg * 8];
    *(uint4*)&Qs[r * 64 + (((cg ^ fswz(r)) & 7) << 3)] = qv;
  }
  __syncthreads();
  const int rsel = ln & 15, ko = (ln >> 4) * 8;
  bf16x8 qf[2];
  #pragma unroll
  for (int kw = 0; kw < 2; ++kw)
    qf[kw] = *(const bf16x8*)&Qs[swz(w * 16 + rsel, ko + 32 * kw)];

  f32x4 acc2[4] = {};          // O[q=(ln>>4)*4+i][d=16n+rsel]
  float m = -1e30f, l = 0.f;   // per-lane state for q-row = rsel (scores pre-scaled)

  // preload KV tile 0: 512 granules each, 1/thread
  const int r0 = t >> 3, cg0 = t & 7;
  uint4 kg = *(const uint4*)&Kb[(size_t)r0 * DK + cg0 * 8];
  uint4 vg = *(const uint4*)&Vb[(size_t)r0 * DK + cg0 * 8];

  for (int c0 = 0; c0 < SQ; c0 += 64) {
    __syncthreads();  // previous tile's Ks/Vt reads done
    *(uint4*)&Ks[r0 * 64 + (((cg0 ^ fswz(r0)) & 7) << 3)] = kg;
    {
      const unsigned short* vv = (const unsigned short*)&vg;
      const int d0 = cg0 * 8;
      #pragma unroll
      for (int e = 0; e < 8; ++e)
        Vt[swz(d0 + e, r0)] = vv[e];   // transpose write, <=2-way banks
    }
    __syncthreads();

    if (c0 + 64 < SQ) {  // prefetch next KV tile under compute
      kg = *(const uint4*)&Kb[(size_t)(c0 + 64 + r0) * DK + cg0 * 8];
      vg = *(const uint4*)&Vb[(size_t)(c0 + 64 + r0) * DK + cg0 * 8];
    }

    // QK^T (swapped): lane holds S[kv=fr*16+(ln>>4)*4+i][q=rsel], pre-scaled
    f32x4 s[4] = {};
    #pragma unroll
    for (int kw = 0; kw < 2; ++kw)
      #pragma unroll
      for (int fr = 0; fr < 4; ++fr) {
        bf16x8 kf = *(const bf16x8*)&Ks[swz(fr * 16 + rsel, ko + 32 * kw)];
        s[fr] = __builtin_amdgcn_mfma_f32_16x16x32_bf16(kf, qf[kw], s[fr], 0, 0, 0);
      }

    // row max, tree-structured (max3-fusable), then cross-replica combine
    float t0 = fmaxf(fmaxf(s[0][0], s[0][1]), fmaxf(s[0][2], s[0][3]));
    float t1 = fmaxf(fmaxf(s[1][0], s[1][1]), fmaxf(s[1][2], s[1][3]));
    float t2 = fmaxf(fmaxf(s[2][0], s[2][1]), fmaxf(s[2][2], s[2][3]));
    float t3 = fmaxf(fmaxf(s[3][0], s[3][1]), fmaxf(s[3][2], s[3][3]));
    float tm = fmaxf(fmaxf(t0, t1), fmaxf(t2, t3));
    tm = fmaxf(tm, __shfl_xor(tm, 16));
    tm = fmaxf(tm, __shfl_xor(tm, 32));

    // defer-max: only rescale when some row's max grew by > 8 (P <= e^8)
    if (__any((tm - m) > 8.f)) {
      const float mnew = fmaxf(m, tm);
      const float corr = __expf(m - mnew);
      float ci[4];
      #pragma unroll
      for (int i = 0; i < 4; ++i) ci[i] = __shfl(corr, (ln >> 4) * 4 + i);
      #pragma unroll
      for (int n = 0; n < 4; ++n)
        #pragma unroll
        for (int i = 0; i < 4; ++i) acc2[n][i] *= ci[i];
      l *= corr;
      m = mnew;
    }

    float p[4][4];
    #pragma unroll
    for (int fr = 0; fr < 4; ++fr)
      #pragma unroll
      for (int i = 0; i < 4; ++i)
        p[fr][i] = __expf(s[fr][i] - m);
    float a0 = (p[0][0] + p[0][1]) + (p[0][2] + p[0][3]);
    float a1 = (p[1][0] + p[1][1]) + (p[1][2] + p[1][3]);
    float a2 = (p[2][0] + p[2][1]) + (p[2][2] + p[2][3]);
    float a3 = (p[3][0] + p[3][1]) + (p[3][2] + p[3][3]);
    float ps = (a0 + a1) + (a2 + a3);
    ps += __shfl_xor(ps, 16);
    ps += __shfl_xor(ps, 32);
    l += ps;

    // pack P (v_cvt_pk_bf16_f32: lo->[15:0], hi->[31:16]) and write to LDS
    #pragma unroll
    for (int fr = 0; fr < 4; ++fr) {
      unsigned r01, r23;
      asm("v_cvt_pk_bf16_f32 %0, %1, %2" : "=v"(r01) : "v"(p[fr][0]), "v"(p[fr][1]));
      asm("v_cvt_pk_bf16_f32 %0, %1, %2" : "=v"(r23) : "v"(p[fr][2]), "v"(p[fr][3]));
      uint2 pv = {r01, r23};
      const int kk0 = (ln >> 4) * 4 + fr * 16;
      *(uint2*)&Pl[w * 1024 + swz(rsel, kk0)] = pv;
    }

    // PV: A = P rows (wave-local region), B = Vt rows
    #pragma unroll
    for (int kw = 0; kw < 2; ++kw) {
      bf16x8 pf = *(const bf16x8*)&Pl[w * 1024 + swz(rsel, ko + 32 * kw)];
      #pragma unroll
      for (int n = 0; n < 4; ++n) {
        bf16x8 vf = *(const bf16x8*)&Vt[swz(n * 16 + rsel, ko + 32 * kw)];
        acc2[n] = __builtin_amdgcn_mfma_f32_16x16x32_bf16(pf, vf, acc2[n], 0, 0, 0);
      }
    }
  }

  // epilogue: divide by l (per output row) and store bf16 ctx [B][S][DM]
  const float rl = 1.0f / l;
  float ri[4];
  #pragma unroll
  for (int i = 0; i < 4; ++i) ri[i] = __shfl(rl, (ln >> 4) * 4 + i);
  const int b = bh >> 4, h = bh & 15;
  #pragma unroll
  for (int n = 0; n < 4; ++n)
    #pragma unroll
    for (int i = 0; i < 4; ++i) {
      const int srow = q0 + w * 16 + (ln >> 4) * 4 + i;
      ctx[((size_t)(b * SQ + srow)) * DM + h * 64 + n * 16 + rsel] =
          f2bf(acc2[n][i] * ri[i]);
    }
}

extern "C" void kernel_launch(void* const* d_in, const int* in_sizes, int n_in,
                              void* d_out, int out_size, void* d_ws, size_t ws_size,
                              hipStream_t stream) {
  const float* x  = (const float*)d_in[0];
  const float* Wq = (const float*)d_in[1];
  const float* bq = (const float*)d_in[2];
  const float* Wk = (const float*)d_in[3];
  const float* bk = (const float*)d_in[4];
  const float* Wv = (const float*)d_in[5];
  const float* bv = (const float*)d_in[6];
  const float* Wo = (const float*)d_in[7];
  const float* bo = (const float*)d_in[8];
  float* out = (float*)d_out;

  unsigned short* xb   = (unsigned short*)d_ws;            // [MR,DM] bf16, 8MB
  unsigned short* Wtq  = xb  + (size_t)MR * DM;            // [N,K] bf16, 2MB each
  unsigned short* Wtk  = Wtq + (size_t)DM * DM;
  unsigned short* Wtv  = Wtk + (size_t)DM * DM;
  unsigned short* Wto  = Wtv + (size_t)DM * DM;
  unsigned short* Qb   = Wto + (size_t)DM * DM;            // [B,H,S,DK] bf16, 8MB each
  unsigned short* Kb   = Qb  + (size_t)MR * DM;
  unsigned short* Vb   = Kb  + (size_t)MR * DM;
  unsigned short* ctxb = Vb  + (size_t)MR * DM;            // [B,S,DM] bf16, 8MB
  // total 48 MB

  cast_kernel<<<(MR * DM / 8 + 255) / 256, 256, 0, stream>>>(x, xb, MR * DM / 8);
  dim3 tg(DM / 32, DM / 32);
  transpose_cast_kernel<<<tg, 256, 0, stream>>>(Wq, Wtq);
  transpose_cast_kernel<<<tg, 256, 0, stream>>>(Wk, Wtk);
  transpose_cast_kernel<<<tg, 256, 0, stream>>>(Wv, Wtv);
  transpose_cast_kernel<<<tg, 256, 0, stream>>>(Wo, Wto);

  dim3 gg(DM / 128, MR / 128);  // (8, 32) = 256 blocks
  mfma_gemm<3><<<gg, 256, 0, stream>>>(xb, Wtq, bq, Qb);   // Q, scale folded
  mfma_gemm<1><<<gg, 256, 0, stream>>>(xb, Wtk, bk, Kb);
  mfma_gemm<1><<<gg, 256, 0, stream>>>(xb, Wtv, bv, Vb);

  attn_mfma<<<dim3(SQ / 128, BB * NH), 512, 0, stream>>>(Qb, Kb, Vb, ctxb);

  mfma_gemm<0><<<gg, 256, 0, stream>>>(ctxb, Wto, bo, out);
}

// Round 11
// 155.688 us; speedup vs baseline: 2.5555x; 1.1319x over previous
//
#include <hip/hip_runtime.h>
#include <hip/hip_bf16.h>
#include <math.h>

constexpr int DM = 1024;    // d_model
constexpr int NH = 16;      // heads
constexpr int DK = 64;      // head dim
constexpr int SQ = 2048;    // seq len
constexpr int BB = 2;       // batch
constexpr int MR = BB * SQ; // 4096 rows

typedef short bf16x8 __attribute__((ext_vector_type(8)));
typedef float f32x4 __attribute__((ext_vector_type(4)));

__device__ inline unsigned short f2bf(float f) {
  unsigned u = __float_as_uint(f);
  unsigned r = (u + 0x7fffu + ((u >> 16) & 1u)) >> 16;  // RNE
  return (unsigned short)r;
}

// XOR swizzle for [R][64] bf16 LDS tiles. f(r) xors the 16B-granule index.
__device__ inline int fswz(int r) { return (r & 7) ^ ((r >> 3) & 7); }
__device__ inline int swz(int r, int c) {
  return r * 64 + ((((c >> 3) ^ fswz(r)) & 7) << 3) + (c & 7);
}

// -------- cast f32 -> bf16, 8 elems/thread --------
__global__ __launch_bounds__(256)
void cast_kernel(const float* __restrict__ in, unsigned short* __restrict__ out, int n8) {
  int i = blockIdx.x * 256 + threadIdx.x;
  if (i >= n8) return;
  float4 a = *(const float4*)&in[(size_t)i * 8];
  float4 b = *(const float4*)&in[(size_t)i * 8 + 4];
  ushort4 lo = {f2bf(a.x), f2bf(a.y), f2bf(a.z), f2bf(a.w)};
  ushort4 hi = {f2bf(b.x), f2bf(b.y), f2bf(b.z), f2bf(b.w)};
  *(ushort4*)&out[(size_t)i * 8] = lo;
  *(ushort4*)&out[(size_t)i * 8 + 4] = hi;
}

// -------- cast+transpose: W[K][N] f32 -> Wt[N][K] bf16 (32x32 tiles) --------
__global__ __launch_bounds__(256)
void transpose_cast_kernel(const float* __restrict__ W, unsigned short* __restrict__ Wt) {
  __shared__ float tl[32][33];
  const int tx = threadIdx.x & 31, ty = threadIdx.x >> 5;  // 32 x 8
  const int x0 = blockIdx.x * 32, y0 = blockIdx.y * 32;    // x0: n, y0: k
  #pragma unroll
  for (int i = 0; i < 4; ++i)
    tl[ty + i * 8][tx] = W[(size_t)(y0 + ty + i * 8) * DM + x0 + tx];
  __syncthreads();
  #pragma unroll
  for (int i = 0; i < 4; ++i)
    Wt[(size_t)(x0 + ty + i * 8) * DM + y0 + tx] = f2bf(tl[tx][ty + i * 8]);
}

// -------- concat bias [bq|bk|bv] -> cb[3072] --------
__global__ __launch_bounds__(256)
void concat_bias(const float* __restrict__ bq, const float* __restrict__ bk,
                 const float* __restrict__ bv, float* __restrict__ cb) {
  int i = blockIdx.x * 256 + threadIdx.x;
  if (i < 1024) cb[i] = bq[i];
  else if (i < 2048) cb[i] = bk[i - 1024];
  else if (i < 3072) cb[i] = bv[i - 2048];
}

// -------- fused QKV GEMM: [4096,1024] x Wt3[3072,1024]^T, 2-phase dbuf --------
// Writes qkv base: Q at +0 (scaled 1/8), K at +MR*DM, V at +2*MR*DM, each [B,H,S,DK].
__global__ __launch_bounds__(256)
void qkv_gemm(const unsigned short* __restrict__ A, const unsigned short* __restrict__ Wt3,
              const float* __restrict__ cbias, unsigned short* __restrict__ qkv)
{
  constexpr int K = DM;
  __shared__ unsigned short As[2][128 * 64];
  __shared__ unsigned short Bs[2][128 * 64];
  const int t = threadIdx.x;
  const int w = t >> 6, ln = t & 63;
  const int wr = w >> 1, wc = w & 1;
  const int rb = blockIdx.y * 128, cb = blockIdx.x * 128;

  f32x4 acc[4][4] = {};

  auto stage = [&](int buf, int k0) {
    #pragma unroll
    for (int j = 0; j < 4; ++j) {
      const int rows8 = (w * 4 + j) * 8;
      const int r = rows8 + (ln >> 3);
      const int gc = (((ln & 7) ^ fswz(r)) & 7) * 8;
      __builtin_amdgcn_global_load_lds(
          (const __attribute__((address_space(1))) void*)&A[(size_t)(rb + r) * K + k0 + gc],
          (__attribute__((address_space(3))) void*)&As[buf][rows8 * 64], 16, 0, 0);
      __builtin_amdgcn_global_load_lds(
          (const __attribute__((address_space(1))) void*)&Wt3[(size_t)(cb + r) * K + k0 + gc],
          (__attribute__((address_space(3))) void*)&Bs[buf][rows8 * 64], 16, 0, 0);
    }
  };

  stage(0, 0);
  asm volatile("s_waitcnt vmcnt(0)" ::: "memory");
  __builtin_amdgcn_s_barrier();

  for (int it = 0; it < K / 64; ++it) {
    const int buf = it & 1;
    if (it < K / 64 - 1) stage(buf ^ 1, (it + 1) * 64);
    const int rsel = ln & 15;
    #pragma unroll
    for (int kk = 0; kk < 2; ++kk) {
      const int ko = kk * 32 + (ln >> 4) * 8;
      bf16x8 af[4], bfr[4];
      #pragma unroll
      for (int m = 0; m < 4; ++m)
        af[m] = *(const bf16x8*)&As[buf][swz(wr * 64 + m * 16 + rsel, ko)];
      #pragma unroll
      for (int n = 0; n < 4; ++n)
        bfr[n] = *(const bf16x8*)&Bs[buf][swz(wc * 64 + n * 16 + rsel, ko)];
      #pragma unroll
      for (int m = 0; m < 4; ++m)
        #pragma unroll
        for (int n = 0; n < 4; ++n)
          acc[m][n] = __builtin_amdgcn_mfma_f32_16x16x32_bf16(af[m], bfr[n], acc[m][n], 0, 0, 0);
    }
    asm volatile("s_waitcnt vmcnt(0)" ::: "memory");
    __builtin_amdgcn_s_barrier();
  }

  const int cl = ln & 15, rg = (ln >> 4) * 4;
  const int which = cb >> 10;                 // 0=Q 1=K 2=V (block-uniform)
  const float sc = (which == 0) ? 0.125f : 1.0f;
  unsigned short* dst0 = qkv + (size_t)which * MR * DM;
  #pragma unroll
  for (int m = 0; m < 4; ++m) {
    #pragma unroll
    for (int i = 0; i < 4; ++i) {
      const int r = rb + wr * 64 + m * 16 + rg + i;
      const int b = r >> 11, s = r & 2047;
      #pragma unroll
      for (int n = 0; n < 4; ++n) {
        const int c = cb + wc * 64 + n * 16 + cl;
        const float v = (acc[m][n][i] + cbias[c]) * sc;
        const int cc = c & 1023, h = cc >> 6, d = c & 63;
        dst0[(((size_t)(b * NH + h)) * SQ + s) * DK + d] = f2bf(v);
      }
    }
  }
}

// -------- bf16 MFMA GEMM (final projection), 2-phase dbuf --------
__global__ __launch_bounds__(256)
void mfma_gemm_out(const unsigned short* __restrict__ A, const unsigned short* __restrict__ Bt,
                   const float* __restrict__ bias, float* __restrict__ outp)
{
  constexpr int K = DM, N = DM;
  __shared__ unsigned short As[2][128 * 64];
  __shared__ unsigned short Bs[2][128 * 64];
  const int t = threadIdx.x;
  const int w = t >> 6, ln = t & 63;
  const int wr = w >> 1, wc = w & 1;
  const int rb = blockIdx.y * 128, cb = blockIdx.x * 128;

  f32x4 acc[4][4] = {};

  auto stage = [&](int buf, int k0) {
    #pragma unroll
    for (int j = 0; j < 4; ++j) {
      const int rows8 = (w * 4 + j) * 8;
      const int r = rows8 + (ln >> 3);
      const int gc = (((ln & 7) ^ fswz(r)) & 7) * 8;
      __builtin_amdgcn_global_load_lds(
          (const __attribute__((address_space(1))) void*)&A[(size_t)(rb + r) * K + k0 + gc],
          (__attribute__((address_space(3))) void*)&As[buf][rows8 * 64], 16, 0, 0);
      __builtin_amdgcn_global_load_lds(
          (const __attribute__((address_space(1))) void*)&Bt[(size_t)(cb + r) * K + k0 + gc],
          (__attribute__((address_space(3))) void*)&Bs[buf][rows8 * 64], 16, 0, 0);
    }
  };

  stage(0, 0);
  asm volatile("s_waitcnt vmcnt(0)" ::: "memory");
  __builtin_amdgcn_s_barrier();

  for (int it = 0; it < K / 64; ++it) {
    const int buf = it & 1;
    if (it < K / 64 - 1) stage(buf ^ 1, (it + 1) * 64);
    const int rsel = ln & 15;
    #pragma unroll
    for (int kk = 0; kk < 2; ++kk) {
      const int ko = kk * 32 + (ln >> 4) * 8;
      bf16x8 af[4], bfr[4];
      #pragma unroll
      for (int m = 0; m < 4; ++m)
        af[m] = *(const bf16x8*)&As[buf][swz(wr * 64 + m * 16 + rsel, ko)];
      #pragma unroll
      for (int n = 0; n < 4; ++n)
        bfr[n] = *(const bf16x8*)&Bs[buf][swz(wc * 64 + n * 16 + rsel, ko)];
      #pragma unroll
      for (int m = 0; m < 4; ++m)
        #pragma unroll
        for (int n = 0; n < 4; ++n)
          acc[m][n] = __builtin_amdgcn_mfma_f32_16x16x32_bf16(af[m], bfr[n], acc[m][n], 0, 0, 0);
    }
    asm volatile("s_waitcnt vmcnt(0)" ::: "memory");
    __builtin_amdgcn_s_barrier();
  }

  const int cl = ln & 15, rg = (ln >> 4) * 4;
  #pragma unroll
  for (int m = 0; m < 4; ++m) {
    #pragma unroll
    for (int i = 0; i < 4; ++i) {
      const int r = rb + wr * 64 + m * 16 + rg + i;
      #pragma unroll
      for (int n = 0; n < 4; ++n) {
        const int c = cb + wc * 64 + n * 16 + cl;
        outp[(size_t)r * N + c] = acc[m][n][i] + bias[c];
      }
    }
  }
}

// -------- MFMA flash attention: 8 waves, QBLK=128, K/V LDS double-buffer --------
// Q pre-scaled 1/8. One barrier per KV tile; setprio around MFMA clusters.
__global__ __launch_bounds__(512, 4)
void attn_mfma(const unsigned short* __restrict__ Qp, const unsigned short* __restrict__ Kp,
               const unsigned short* __restrict__ Vp, unsigned short* __restrict__ ctx)
{
  __shared__ unsigned short Qs[128 * 64];       // 16KB
  __shared__ unsigned short Ks[2][64 * 64];     // 16KB
  __shared__ unsigned short Vt[2][64 * 64];     // 16KB  V^T: [d][kv]
  __shared__ unsigned short Pl[8 * 16 * 64];    // 16KB per-wave P: [q][kk]
  const int t = threadIdx.x, w = t >> 6, ln = t & 63;
  const int bh = blockIdx.y, q0 = blockIdx.x * 128;
  const unsigned short* Qb = Qp + (size_t)bh * SQ * DK;
  const unsigned short* Kb = Kp + (size_t)bh * SQ * DK;
  const unsigned short* Vb = Vp + (size_t)bh * SQ * DK;

  // stage Q tile: 128 rows x 64 = 1024 granules, 2/thread (512 threads)
  #pragma unroll
  for (int i = 0; i < 2; ++i) {
    int g = t + i * 512, r = g >> 3, cg = g & 7;
    uint4 qv = *(const uint4*)&Qb[(size_t)(q0 + r) * DK + cg * 8];
    *(uint4*)&Qs[r * 64 + (((cg ^ fswz(r)) & 7) << 3)] = qv;
  }
  __syncthreads();
  const int rsel = ln & 15, ko = (ln >> 4) * 8;
  bf16x8 qf[2];
  #pragma unroll
  for (int kw = 0; kw < 2; ++kw)
    qf[kw] = *(const bf16x8*)&Qs[swz(w * 16 + rsel, ko + 32 * kw)];

  f32x4 acc2[4] = {};          // O[q=(ln>>4)*4+i][d=16n+rsel]
  float m = -1e30f, l = 0.f;

  // stage KV tile 0 into buf 0
  const int r0 = t >> 3, cg0 = t & 7;
  const int ksl = r0 * 64 + (((cg0 ^ fswz(r0)) & 7) << 3);
  {
    uint4 kg = *(const uint4*)&Kb[(size_t)r0 * DK + cg0 * 8];
    uint4 vg = *(const uint4*)&Vb[(size_t)r0 * DK + cg0 * 8];
    *(uint4*)&Ks[0][ksl] = kg;
    const unsigned short* vv = (const unsigned short*)&vg;
    #pragma unroll
    for (int e = 0; e < 8; ++e)
      Vt[0][swz(cg0 * 8 + e, r0)] = vv[e];
  }
  __syncthreads();

  int cur = 0;
  for (int c0 = 0; c0 < SQ; c0 += 64) {
    const bool haveNext = (c0 + 64 < SQ);
    uint4 kg, vg;
    if (haveNext) {  // issue next-tile loads early; land under compute
      kg = *(const uint4*)&Kb[(size_t)(c0 + 64 + r0) * DK + cg0 * 8];
      vg = *(const uint4*)&Vb[(size_t)(c0 + 64 + r0) * DK + cg0 * 8];
    }

    // QK^T (swapped): lane holds S[kv=fr*16+(ln>>4)*4+i][q=rsel], pre-scaled
    f32x4 s[4] = {};
    __builtin_amdgcn_s_setprio(1);
    #pragma unroll
    for (int kw = 0; kw < 2; ++kw)
      #pragma unroll
      for (int fr = 0; fr < 4; ++fr) {
        bf16x8 kf = *(const bf16x8*)&Ks[cur][swz(fr * 16 + rsel, ko + 32 * kw)];
        s[fr] = __builtin_amdgcn_mfma_f32_16x16x32_bf16(kf, qf[kw], s[fr], 0, 0, 0);
      }
    __builtin_amdgcn_s_setprio(0);

    // row max (tree), cross-replica combine
    float t0 = fmaxf(fmaxf(s[0][0], s[0][1]), fmaxf(s[0][2], s[0][3]));
    float t1 = fmaxf(fmaxf(s[1][0], s[1][1]), fmaxf(s[1][2], s[1][3]));
    float t2 = fmaxf(fmaxf(s[2][0], s[2][1]), fmaxf(s[2][2], s[2][3]));
    float t3 = fmaxf(fmaxf(s[3][0], s[3][1]), fmaxf(s[3][2], s[3][3]));
    float tm = fmaxf(fmaxf(t0, t1), fmaxf(t2, t3));
    tm = fmaxf(tm, __shfl_xor(tm, 16));
    tm = fmaxf(tm, __shfl_xor(tm, 32));

    // defer-max: rescale only when some row's max grew by > 8
    if (__any((tm - m) > 8.f)) {
      const float mnew = fmaxf(m, tm);
      const float corr = __expf(m - mnew);
      float ci[4];
      #pragma unroll
      for (int i = 0; i < 4; ++i) ci[i] = __shfl(corr, (ln >> 4) * 4 + i);
      #pragma unroll
      for (int n = 0; n < 4; ++n)
        #pragma unroll
        for (int i = 0; i < 4; ++i) acc2[n][i] *= ci[i];
      l *= corr;
      m = mnew;
    }

    float p[4][4];
    #pragma unroll
    for (int fr = 0; fr < 4; ++fr)
      #pragma unroll
      for (int i = 0; i < 4; ++i)
        p[fr][i] = __expf(s[fr][i] - m);
    float a0 = (p[0][0] + p[0][1]) + (p[0][2] + p[0][3]);
    float a1 = (p[1][0] + p[1][1]) + (p[1][2] + p[1][3]);
    float a2 = (p[2][0] + p[2][1]) + (p[2][2] + p[2][3]);
    float a3 = (p[3][0] + p[3][1]) + (p[3][2] + p[3][3]);
    float ps = (a0 + a1) + (a2 + a3);
    ps += __shfl_xor(ps, 16);
    ps += __shfl_xor(ps, 32);
    l += ps;

    // pack P (v_cvt_pk_bf16_f32) and write to this wave's LDS region
    #pragma unroll
    for (int fr = 0; fr < 4; ++fr) {
      unsigned r01, r23;
      asm("v_cvt_pk_bf16_f32 %0, %1, %2" : "=v"(r01) : "v"(p[fr][0]), "v"(p[fr][1]));
      asm("v_cvt_pk_bf16_f32 %0, %1, %2" : "=v"(r23) : "v"(p[fr][2]), "v"(p[fr][3]));
      uint2 pv = {r01, r23};
      const int kk0 = (ln >> 4) * 4 + fr * 16;
      *(uint2*)&Pl[w * 1024 + swz(rsel, kk0)] = pv;
    }

    // PV: A = P rows (wave-local), B = Vt[cur] rows
    __builtin_amdgcn_s_setprio(1);
    #pragma unroll
    for (int kw = 0; kw < 2; ++kw) {
      bf16x8 pf = *(const bf16x8*)&Pl[w * 1024 + swz(rsel, ko + 32 * kw)];
      #pragma unroll
      for (int n = 0; n < 4; ++n) {
        bf16x8 vf = *(const bf16x8*)&Vt[cur][swz(n * 16 + rsel, ko + 32 * kw)];
        acc2[n] = __builtin_amdgcn_mfma_f32_16x16x32_bf16(pf, vf, acc2[n], 0, 0, 0);
      }
    }
    __builtin_amdgcn_s_setprio(0);

    if (haveNext) {
      // write next tile into the other buffer (its last readers finished
      // before the barrier at the end of the previous iteration)
      *(uint4*)&Ks[cur ^ 1][ksl] = kg;
      const unsigned short* vv = (const unsigned short*)&vg;
      #pragma unroll
      for (int e = 0; e < 8; ++e)
        Vt[cur ^ 1][swz(cg0 * 8 + e, r0)] = vv[e];
      __syncthreads();  // one barrier per tile
    }
    cur ^= 1;
  }

  // epilogue: divide by l and store bf16 ctx [B][S][DM]
  const float rl = 1.0f / l;
  float ri[4];
  #pragma unroll
  for (int i = 0; i < 4; ++i) ri[i] = __shfl(rl, (ln >> 4) * 4 + i);
  const int b = bh >> 4, h = bh & 15;
  #pragma unroll
  for (int n = 0; n < 4; ++n)
    #pragma unroll
    for (int i = 0; i < 4; ++i) {
      const int srow = q0 + w * 16 + (ln >> 4) * 4 + i;
      ctx[((size_t)(b * SQ + srow)) * DM + h * 64 + n * 16 + rsel] =
          f2bf(acc2[n][i] * ri[i]);
    }
}

extern "C" void kernel_launch(void* const* d_in, const int* in_sizes, int n_in,
                              void* d_out, int out_size, void* d_ws, size_t ws_size,
                              hipStream_t stream) {
  const float* x  = (const float*)d_in[0];
  const float* Wq = (const float*)d_in[1];
  const float* bq = (const float*)d_in[2];
  const float* Wk = (const float*)d_in[3];
  const float* bk = (const float*)d_in[4];
  const float* Wv = (const float*)d_in[5];
  const float* bv = (const float*)d_in[6];
  const float* Wo = (const float*)d_in[7];
  const float* bo = (const float*)d_in[8];
  float* out = (float*)d_out;

  unsigned short* xb    = (unsigned short*)d_ws;             // [MR,DM] bf16, 8MB
  unsigned short* Wt3   = xb   + (size_t)MR * DM;            // [3072,1024] bf16, 6MB
  unsigned short* Wto   = Wt3  + (size_t)3 * DM * DM;        // [1024,1024] bf16, 2MB
  unsigned short* QKVb  = Wto  + (size_t)DM * DM;            // 3x [B,H,S,DK] bf16, 24MB
  unsigned short* ctxb  = QKVb + (size_t)3 * MR * DM;        // [B,S,DM] bf16, 8MB
  float*          cbias = (float*)(ctxb + (size_t)MR * DM);  // [3072] f32
  // total ~48 MB

  cast_kernel<<<(MR * DM / 8 + 255) / 256, 256, 0, stream>>>(x, xb, MR * DM / 8);
  dim3 tg(DM / 32, DM / 32);
  transpose_cast_kernel<<<tg, 256, 0, stream>>>(Wq, Wt3);
  transpose_cast_kernel<<<tg, 256, 0, stream>>>(Wk, Wt3 + (size_t)DM * DM);
  transpose_cast_kernel<<<tg, 256, 0, stream>>>(Wv, Wt3 + (size_t)2 * DM * DM);
  transpose_cast_kernel<<<tg, 256, 0, stream>>>(Wo, Wto);
  concat_bias<<<12, 256, 0, stream>>>(bq, bk, bv, cbias);

  qkv_gemm<<<dim3(3 * DM / 128, MR / 128), 256, 0, stream>>>(xb, Wt3, cbias, QKVb);

  attn_mfma<<<dim3(SQ / 128, BB * NH), 512, 0, stream>>>(
      QKVb, QKVb + (size_t)MR * DM, QKVb + (size_t)2 * MR * DM, ctxb);

  mfma_gemm_out<<<dim3(DM / 128, MR / 128), 256, 0, stream>>>(ctxb, Wto, bo, out);
}